// Round 6
// baseline (272.787 us; speedup 1.0000x reference)
//
#include <hip/hip_runtime.h>

// N=65536, D_IN=1024, D_LAT=128, K=512
#define NROWS 65536
#define DIN   1024
#define DLAT  128
#define KC    512

typedef __attribute__((ext_vector_type(8))) short bf16x8;
typedef __attribute__((ext_vector_type(4))) float f32x4;

// direct global->LDS DMA, 16B per lane, LDS dest = wave-uniform base + lane*16
#define GLDS16(gp, lp)                                                          \
    __builtin_amdgcn_global_load_lds((const __attribute__((address_space(1))) void*)(gp), \
                                     (__attribute__((address_space(3))) void*)(lp), 16, 0, 0)

__device__ inline short f2bf(float f) {
    unsigned u = __float_as_uint(f);
    return (short)((u + 0x7FFFu + ((u >> 16) & 1u)) >> 16);  // RNE f32->bf16
}

// ---------- prep: Wt[n][k] = bf16(W[k][n]); cb = bf16(centroids) ----------
__global__ __launch_bounds__(256) void prep_convert(const float* __restrict__ W,
                                                    const float* __restrict__ C,
                                                    short* __restrict__ Wt,
                                                    short* __restrict__ cb) {
    int idx = blockIdx.x * 256 + threadIdx.x;
    if (idx < DLAT * DIN) {                 // 131072 elements of Wt
        int n = idx >> 10, k = idx & 1023;  // Wt[n][k] = W[k][n]
        Wt[idx] = f2bf(W[k * DLAT + n]);
    } else {
        int i2 = idx - DLAT * DIN;
        if (i2 < KC * DLAT) cb[i2] = f2bf(C[i2]);
    }
}

// ---------- prep: csq[k] = ||centroid_k||^2 ----------
__global__ __launch_bounds__(64) void prep_csq(const float* __restrict__ C,
                                               float* __restrict__ csq) {
    int row = blockIdx.x;
    int lane = threadIdx.x;  // 0..63
    float a = C[row * DLAT + lane];
    float b = C[row * DLAT + 64 + lane];
    float s = a * a + b * b;
    #pragma unroll
    for (int m = 32; m >= 1; m >>= 1) s += __shfl_xor(s, m, 64);
    if (lane == 0) csq[row] = s;
}

// ---------- FUSED: l = x@W+b  ->  S=l@c^T -> Q -> Fq partials ----------
// Phase 1 = r3's best gemm1 (BK=64, 2-buffer global_load_lds, 64KB LDS) verbatim.
// Phase 1.5: acc (+bias) -> global l AND slot-swizzled LDS transpose (overlays buf0).
// Phase 2 = gemm2_q reading l from LDS (zero HBM re-read).
// Cross-block overlap: while one resident block streams x, the other runs phase-2 compute.
__global__ __launch_bounds__(256, 2) void fused_aq(const float* __restrict__ x,
                                                   const short* __restrict__ Wt,
                                                   const float* __restrict__ bias,
                                                   const short* __restrict__ cb,
                                                   const float* __restrict__ csq,
                                                   float* __restrict__ lout,
                                                   float* __restrict__ Qout,
                                                   float* __restrict__ partial) {
    __shared__ char lds[65536];
    const int t = threadIdx.x;
    const int wid = t >> 6, lane = t & 63;
    const int l16 = lane & 15, lhi = lane >> 4;
    const int row0 = blockIdx.x * 64;

    // ---- phase 1: l-GEMM (identical to r3 gemm1) ----
    const float* xsrc = x + (long)(row0 + (t >> 4)) * DIN + (((t & 15) ^ ((t >> 4) & 15)) << 2);
    const short* wsrc = Wt + (long)(t >> 3) * DIN + (((t & 7) ^ ((t >> 3) & 7)) << 3);
    const int lofs = t * 16;

    f32x4 acc[8];
    #pragma unroll
    for (int i = 0; i < 8; ++i) acc[i] = (f32x4){0.f, 0.f, 0.f, 0.f};

    {
        char* xb = lds;
        char* wb = lds + 16384;
        #pragma unroll
        for (int j = 0; j < 4; ++j) {
            GLDS16(xsrc + j * 16 * DIN, xb + lofs + j * 4096);
            GLDS16(wsrc + j * 32 * DIN, wb + lofs + j * 4096);
        }
    }
    __syncthreads();

    int cur = 0;
    const int arow = wid * 16 + l16;
    for (int kc = 0; kc < 16; ++kc) {
        if (kc < 15) {
            char* xb = lds + (cur ^ 1) * 32768;
            char* wb = xb + 16384;
            const float* xp = xsrc + (kc + 1) * 64;
            const short* wp = wsrc + (kc + 1) * 64;
            #pragma unroll
            for (int j = 0; j < 4; ++j) {
                GLDS16(xp + j * 16 * DIN, xb + lofs + j * 4096);
                GLDS16(wp + j * 32 * DIN, wb + lofs + j * 4096);
            }
        }
        const float* xs = (const float*)(lds + cur * 32768);
        const short* wl = (const short*)(lds + cur * 32768 + 16384);
        #pragma unroll
        for (int ks = 0; ks < 2; ++ks) {
            const int c4 = ks * 8 + lhi * 2;
            const float4 va0 = *(const float4*)(xs + arow * 64 + ((c4 ^ l16) << 2));
            const float4 va1 = *(const float4*)(xs + arow * 64 + (((c4 + 1) ^ l16) << 2));
            bf16x8 af;
            af[0] = f2bf(va0.x); af[1] = f2bf(va0.y); af[2] = f2bf(va0.z); af[3] = f2bf(va0.w);
            af[4] = f2bf(va1.x); af[5] = f2bf(va1.y); af[6] = f2bf(va1.z); af[7] = f2bf(va1.w);
            const int c8 = ks * 4 + lhi;
            #pragma unroll
            for (int nb = 0; nb < 8; ++nb) {
                const int n = nb * 16 + l16;
                const bf16x8 bf = *(const bf16x8*)(wl + n * 64 + ((c8 ^ (n & 7)) << 3));
                acc[nb] = __builtin_amdgcn_mfma_f32_16x16x32_bf16(af, bf, acc[nb], 0, 0, 0);
            }
        }
        __syncthreads();
        cur ^= 1;
    }

    // ---- phase 1.5: bias; write l to global + swizzled LDS transpose ----
    // l_lds element (row,col) at byte/4: row*128 + ((col>>2)^(row&15))*4 + (col&3)
    float* l_lds = (float*)lds;          // 32KB, overlays buf0 (last read 2 barriers ago)
    #pragma unroll
    for (int nb = 0; nb < 8; ++nb) {
        const int col = nb * 16 + l16;
        const float bv = bias[col];
        const int slot = col >> 2, e = col & 3;
        #pragma unroll
        for (int r = 0; r < 4; ++r) {
            const int row = wid * 16 + lhi * 4 + r;   // block-local; C/D: col=lane&15,row=(lane>>4)*4+r
            const float v = acc[nb][r] + bv;
            lout[(long)(row0 + row) * DLAT + col] = v;
            l_lds[row * 128 + ((slot ^ (row & 15)) << 2) + e] = v;
        }
    }
    __syncthreads();

    // ---- phase 2: S = l@c^T -> num -> Q -> Fq partials ----
    float* lds_fq = (float*)(lds + 32768);   // [4][KC], overlays buf1 (safe after barrier)
    const int row0w = row0 + wid * 16;

    bf16x8 af2[4];
    float sq = 0.f;
    #pragma unroll
    for (int ks = 0; ks < 4; ++ks) {
        const int s0 = 8 * ks + 2 * lhi;
        const float4 v0 = *(const float4*)(l_lds + arow * 128 + ((s0 ^ l16) << 2));
        const float4 v1 = *(const float4*)(l_lds + arow * 128 + (((s0 + 1) ^ l16) << 2));
        sq += v0.x * v0.x + v0.y * v0.y + v0.z * v0.z + v0.w * v0.w
            + v1.x * v1.x + v1.y * v1.y + v1.z * v1.z + v1.w * v1.w;
        bf16x8 a;
        a[0] = f2bf(v0.x); a[1] = f2bf(v0.y); a[2] = f2bf(v0.z); a[3] = f2bf(v0.w);
        a[4] = f2bf(v1.x); a[5] = f2bf(v1.y); a[6] = f2bf(v1.z); a[7] = f2bf(v1.w);
        af2[ks] = a;
    }
    sq += __shfl_xor(sq, 16, 64);
    sq += __shfl_xor(sq, 32, 64);          // lane L holds lsq of row (L&15)
    float lsqr[4];
    #pragma unroll
    for (int r = 0; r < 4; ++r) lsqr[r] = __shfl(sq, lhi * 4 + r, 64);

    f32x4 numv[32];
    float rsum[4] = {0.f, 0.f, 0.f, 0.f};
    #pragma unroll
    for (int nb = 0; nb < 32; ++nb) {
        f32x4 s2 = (f32x4){0.f, 0.f, 0.f, 0.f};
        const short* cbase = cb + (nb * 16 + l16) * DLAT;
        #pragma unroll
        for (int ks = 0; ks < 4; ++ks) {
            const bf16x8 bf = *(const bf16x8*)(cbase + ks * 32 + lhi * 8);
            s2 = __builtin_amdgcn_mfma_f32_16x16x32_bf16(af2[ks], bf, s2, 0, 0, 0);
        }
        const float cs = csq[nb * 16 + l16];
        f32x4 nm;
        #pragma unroll
        for (int r = 0; r < 4; ++r) {
            float Dv = lsqr[r] + cs - 2.f * s2[r];
            float v = 1.f / (1.f + Dv);    // alpha=1: (1+D)^(-1)
            nm[r] = v;
            rsum[r] += v;
        }
        numv[nb] = nm;
    }
    #pragma unroll
    for (int m = 1; m <= 8; m <<= 1) {
        #pragma unroll
        for (int r = 0; r < 4; ++r) rsum[r] += __shfl_xor(rsum[r], m, 64);
    }
    float inv[4];
    #pragma unroll
    for (int r = 0; r < 4; ++r) inv[r] = 1.f / rsum[r];

    #pragma unroll
    for (int nb = 0; nb < 32; ++nb) {
        float cp = 0.f;
        #pragma unroll
        for (int r = 0; r < 4; ++r) {
            float q = numv[nb][r] * inv[r];
            Qout[(long)(row0w + lhi * 4 + r) * KC + nb * 16 + l16] = q;
            cp += q;
        }
        cp += __shfl_xor(cp, 16, 64);
        cp += __shfl_xor(cp, 32, 64);      // colsum over this wave's 16 rows
        if (lhi == 0) lds_fq[wid * KC + nb * 16 + l16] = cp;
    }
    __syncthreads();
    for (int c = t; c < KC; c += 256) {
        partial[(long)blockIdx.x * KC + c] =
            lds_fq[0 * KC + c] + lds_fq[1 * KC + c] + lds_fq[2 * KC + c] + lds_fq[3 * KC + c];
    }
}

// ---------- Fq reduce: fqinv[c] = 1 / sum over 1024 block partials ----------
__global__ __launch_bounds__(256) void fq_reduce(const float* __restrict__ partial,
                                                 float* __restrict__ fqinv) {
    int c = blockIdx.x;
    float s = 0.f;
    #pragma unroll
    for (int i = 0; i < 4; ++i) s += partial[(long)(threadIdx.x + i * 256) * KC + c];
    __shared__ float red[256];
    red[threadIdx.x] = s;
    __syncthreads();
    for (int off = 128; off >= 1; off >>= 1) {
        if (threadIdx.x < off) red[threadIdx.x] += red[threadIdx.x + off];
        __syncthreads();
    }
    if (threadIdx.x == 0) fqinv[c] = 1.f / red[0];
}

// ---------- P pass: recompute nm from l (bit-identical), never re-read Q ----------
// P row is invariant to row-scaling of Q: P = (nm^2/Fq) / rowsum(nm^2/Fq).
__global__ __launch_bounds__(256, 2) void p_recompute(const float* __restrict__ lout,
                                                      const short* __restrict__ cb,
                                                      const float* __restrict__ csq,
                                                      const float* __restrict__ fqinv,
                                                      float* __restrict__ P) {
    const int wid = threadIdx.x >> 6, lane = threadIdx.x & 63;
    const int l16 = lane & 15, lhi = lane >> 4;
    const int row0 = blockIdx.x * 64 + wid * 16;

    bf16x8 af[4];
    float sq = 0.f;
    const float* lrow = lout + (long)(row0 + l16) * DLAT;
    #pragma unroll
    for (int ks = 0; ks < 4; ++ks) {
        const float4* lp = (const float4*)(lrow + ks * 32 + lhi * 8);
        float4 v0 = lp[0], v1 = lp[1];
        sq += v0.x * v0.x + v0.y * v0.y + v0.z * v0.z + v0.w * v0.w
            + v1.x * v1.x + v1.y * v1.y + v1.z * v1.z + v1.w * v1.w;
        bf16x8 a;
        a[0] = f2bf(v0.x); a[1] = f2bf(v0.y); a[2] = f2bf(v0.z); a[3] = f2bf(v0.w);
        a[4] = f2bf(v1.x); a[5] = f2bf(v1.y); a[6] = f2bf(v1.z); a[7] = f2bf(v1.w);
        af[ks] = a;
    }
    sq += __shfl_xor(sq, 16, 64);
    sq += __shfl_xor(sq, 32, 64);
    float lsqr[4];
    #pragma unroll
    for (int r = 0; r < 4; ++r) lsqr[r] = __shfl(sq, lhi * 4 + r, 64);

    f32x4 uv[32];
    float rsum[4] = {0.f, 0.f, 0.f, 0.f};
    #pragma unroll
    for (int nb = 0; nb < 32; ++nb) {
        f32x4 s2 = (f32x4){0.f, 0.f, 0.f, 0.f};
        const short* cbase = cb + (nb * 16 + l16) * DLAT;
        #pragma unroll
        for (int ks = 0; ks < 4; ++ks) {
            const bf16x8 bf = *(const bf16x8*)(cbase + ks * 32 + lhi * 8);
            s2 = __builtin_amdgcn_mfma_f32_16x16x32_bf16(af[ks], bf, s2, 0, 0, 0);
        }
        const float cs = csq[nb * 16 + l16];
        const float fqi = fqinv[nb * 16 + l16];
        f32x4 u;
        #pragma unroll
        for (int r = 0; r < 4; ++r) {
            float Dv = lsqr[r] + cs - 2.f * s2[r];
            float nm = 1.f / (1.f + Dv);        // bit-identical to fused_aq's nm
            float v = nm * nm * fqi;
            u[r] = v;
            rsum[r] += v;
        }
        uv[nb] = u;
    }
    #pragma unroll
    for (int m = 1; m <= 8; m <<= 1) {
        #pragma unroll
        for (int r = 0; r < 4; ++r) rsum[r] += __shfl_xor(rsum[r], m, 64);
    }
    float inv[4];
    #pragma unroll
    for (int r = 0; r < 4; ++r) inv[r] = 1.f / rsum[r];

    #pragma unroll
    for (int nb = 0; nb < 32; ++nb) {
        #pragma unroll
        for (int r = 0; r < 4; ++r) {
            P[(long)(row0 + lhi * 4 + r) * KC + nb * 16 + l16] = uv[nb][r] * inv[r];
        }
    }
}

extern "C" void kernel_launch(void* const* d_in, const int* in_sizes, int n_in,
                              void* d_out, int out_size, void* d_ws, size_t ws_size,
                              hipStream_t stream) {
    const float* x  = (const float*)d_in[0];
    const float* W  = (const float*)d_in[1];
    const float* b  = (const float*)d_in[2];
    const float* C  = (const float*)d_in[3];

    float* out  = (float*)d_out;
    float* lout = out;                                   // 65536*128
    float* Qout = out + (long)NROWS * DLAT;              // 65536*512
    float* Pout = Qout + (long)NROWS * KC;               // 65536*512

    // workspace layout (~2.44 MB)
    char*  ws      = (char*)d_ws;
    short* Wt      = (short*)ws;                         // 131072 * 2 B
    short* cb      = (short*)(ws + 262144);              // 65536 * 2 B
    float* csq     = (float*)(ws + 262144 + 131072);     // 512 * 4 B
    float* partial = (float*)(ws + 395264);              // 1024*512*4 = 2 MB
    float* fqinv   = (float*)(ws + 395264 + 2097152);    // 512 * 4 B

    hipLaunchKernelGGL(prep_convert, dim3(768),  dim3(256), 0, stream, W, C, Wt, cb);
    hipLaunchKernelGGL(prep_csq,     dim3(512),  dim3(64),  0, stream, C, csq);
    hipLaunchKernelGGL(fused_aq,     dim3(1024), dim3(256), 0, stream,
                       x, Wt, b, cb, csq, lout, Qout, partial);
    hipLaunchKernelGGL(fq_reduce,    dim3(512),  dim3(256), 0, stream, partial, fqinv);
    hipLaunchKernelGGL(p_recompute,  dim3(1024), dim3(256), 0, stream,
                       lout, cb, csq, fqinv, Pout);
}